// Round 9
// baseline (276.402 us; speedup 1.0000x reference)
//
#include <hip/hip_runtime.h>
#include <hip/hip_fp16.h>
#include <math.h>

#define HD 128          // hidden dim (= H*C = D_IN)
#define NEG_SLOPE 0.2f
#define EPSV 1e-16f
#define TILE 8192       // edges per partition tile

typedef unsigned short ushort_t;
typedef __attribute__((ext_vector_type(8))) short bf16x8;
typedef __attribute__((ext_vector_type(4))) float f32x4;

// RNE split of fp32 into hi/lo bf16 bit patterns
__device__ inline void bsplit(float x, ushort_t& hi, ushort_t& lo) {
    unsigned u = __float_as_uint(x);
    unsigned hb = (u + 0x7FFFu + ((u >> 16) & 1u)) >> 16;
    hi = (ushort_t)hb;
    float res = x - __uint_as_float(hb << 16);
    unsigned v = __float_as_uint(res);
    lo = (ushort_t)((v + 0x7FFFu + ((v >> 16) & 1u)) >> 16);
}

// ---------------- edge partition by coarse bucket (dst>>8) ----------------
__global__ __launch_bounds__(256) void part_hist(const int* __restrict__ dst,
                                                 int* __restrict__ tileHist, int E) {
    __shared__ int hist[256];
    int t = threadIdx.x;
    hist[t] = 0;
    __syncthreads();
    int base = blockIdx.x * TILE;
    int end = base + TILE; if (end > E) end = E;
    for (int i = base + t; i < end; i += 256)
        atomicAdd(&hist[dst[i] >> 8], 1);
    __syncthreads();
    tileHist[blockIdx.x * 256 + t] = hist[t];
}

__global__ __launch_bounds__(256) void part_offsets(int* __restrict__ tileHist,
                                                    int* __restrict__ bucketBase,
                                                    int NT) {
    __shared__ int s[256];
    int b = threadIdx.x;
    int total = 0;
    #pragma unroll 8
    for (int t = 0; t < NT; ++t) total += tileHist[t * 256 + b];
    s[b] = total;
    __syncthreads();
    for (int o = 1; o < 256; o <<= 1) {
        int v = (b >= o) ? s[b - o] : 0;
        __syncthreads();
        s[b] += v;
        __syncthreads();
    }
    int base = (b == 0) ? 0 : s[b - 1];
    bucketBase[b] = base;
    if (b == 255) bucketBase[256] = s[255];
    int run = base;
    #pragma unroll 8
    for (int t = 0; t < NT; ++t) {
        int v = tileHist[t * 256 + b];
        tileHist[t * 256 + b] = run;
        run += v;
    }
}

// packed entry: (src<<8) | (dst&255)  — src < 2^23 holds for N=50k
__global__ __launch_bounds__(256) void part_scatter(const int* __restrict__ src,
                                                    const int* __restrict__ dst,
                                                    const int* __restrict__ tileHist,
                                                    int* __restrict__ part, int E) {
    __shared__ int cur[256];
    int t = threadIdx.x;
    cur[t] = tileHist[blockIdx.x * 256 + t];
    __syncthreads();
    int base = blockIdx.x * TILE;
    int end = base + TILE; if (end > E) end = E;
    for (int i = base + t; i < end; i += 256) {
        int d = dst[i], s = src[i];
        int p = atomicAdd(&cur[d >> 8], 1);
        part[p] = (s << 8) | (d & 255);
    }
}

// per-node counts (+1 self-loop) AND per-bucket scan input
__global__ __launch_bounds__(256) void fine_counts(const int* __restrict__ part,
                                                   const int* __restrict__ bucketBase,
                                                   int* __restrict__ cnt,
                                                   int* __restrict__ bsum, int N) {
    __shared__ int hist[256];
    int t = threadIdx.x;
    hist[t] = 0;
    __syncthreads();
    int b = blockIdx.x;
    int s0 = bucketBase[b], s1 = bucketBase[b + 1];
    for (int i = s0 + t; i < s1; i += 256)
        atomicAdd(&hist[part[i] & 255], 1);
    __syncthreads();
    int d = b * 256 + t;
    if (d < N) cnt[d] = hist[t] + 1;
    if (t == 0) {
        int nn = N - b * 256; if (nn > 256) nn = 256; if (nn < 0) nn = 0;
        bsum[b] = (s1 - s0) + nn;   // edges in bucket + self-loops
    }
}

// exclusive scan of per-bucket sums (single block, tiles of 256 w/ carry)
__global__ __launch_bounds__(256) void scan_bsums(int* __restrict__ bsum, int NB) {
    __shared__ int s[256];
    __shared__ int carry;
    int t = threadIdx.x;
    if (t == 0) carry = 0;
    __syncthreads();
    for (int base = 0; base < NB; base += 256) {
        int i = base + t;
        int v = (i < NB) ? bsum[i] : 0;
        s[t] = v;
        __syncthreads();
        for (int o = 1; o < 256; o <<= 1) {
            int u = (t >= o) ? s[t - o] : 0;
            __syncthreads();
            s[t] += u;
            __syncthreads();
        }
        int excl = ((t == 0) ? 0 : s[t - 1]) + carry;
        if (i < NB) bsum[i] = excl;
        __syncthreads();
        if (t == 0) carry += s[255];
        __syncthreads();
    }
}

// CSR scatter: in-block exclusive scan of cnt -> indptr + LDS cursors, then scatter
__global__ __launch_bounds__(256) void csr_scatter(const int* __restrict__ part,
                                                   const int* __restrict__ bucketBase,
                                                   const int* __restrict__ cnt,
                                                   const int* __restrict__ bsum,
                                                   int* __restrict__ indptr,
                                                   int* __restrict__ csr, int N) {
    __shared__ int s[256];
    __shared__ int cur[256];
    int t = threadIdx.x;
    int b = blockIdx.x;
    int d = b * 256 + t;
    int v = (d < N) ? cnt[d] : 0;
    s[t] = v;
    __syncthreads();
    for (int o = 1; o < 256; o <<= 1) {
        int u = (t >= o) ? s[t - o] : 0;
        __syncthreads();
        s[t] += u;
        __syncthreads();
    }
    int excl = ((t == 0) ? 0 : s[t - 1]) + bsum[b];
    if (d < N) indptr[d] = excl;
    if (d == N - 1) indptr[N] = excl + v;
    cur[t] = excl;
    __syncthreads();
    int s0 = bucketBase[b], s1 = bucketBase[b + 1];
    for (int i = s0 + t; i < s1; i += 256) {
        int e = part[i];
        int p = atomicAdd(&cur[e & 255], 1);
        csr[p] = e >> 8;
    }
    __syncthreads();
    if (d < N) csr[cur[t]] = d;   // self-loop fills the one remaining slot
}

// ---------------- W split+swizzle into MFMA B-fragment order ----------------
__global__ __launch_bounds__(256) void split_w(const float* __restrict__ W,
                                               ushort_t* __restrict__ Whs,
                                               ushort_t* __restrict__ Wls) {
    int idx = blockIdx.x * 256 + threadIdx.x;   // 0..16383
    int j    = idx & 7;
    int lane = (idx >> 3) & 63;
    int ks   = (idx >> 9) & 3;
    int ct   = idx >> 11;
    int n = ct * 16 + (lane & 15);
    int k = ks * 32 + (lane >> 4) * 8 + j;
    ushort_t hi, lo;
    bsplit(W[k * 128 + n], hi, lo);
    Whs[idx] = hi;
    Wls[idx] = lo;
}

// ---------------- A-row 8-element loaders (fp32 or fp16 input) ----------------
__device__ inline void load8(const float* p, float* vv) {
    float4 a = *(const float4*)p;
    float4 b = *(const float4*)(p + 4);
    vv[0]=a.x; vv[1]=a.y; vv[2]=a.z; vv[3]=a.w;
    vv[4]=b.x; vv[5]=b.y; vv[6]=b.z; vv[7]=b.w;
}
__device__ inline void load8(const __half* p, float* vv) {
    bf16x8 r = *(const bf16x8*)p;
    #pragma unroll
    for (int j = 0; j < 8; ++j)
        vv[j] = __half2float(__ushort_as_half((ushort_t)r[j]));
}

// ---------------- GEMM via split-bf16 MFMA + fused attention logits ----------------
template <typename TA>
__global__ __launch_bounds__(256) void gemm_mfma(const TA* __restrict__ A,
                                                 const ushort_t* __restrict__ Whs,
                                                 const ushort_t* __restrict__ Wls,
                                                 const float* __restrict__ a_s,
                                                 const float* __restrict__ a_d,
                                                 __half* __restrict__ h16,
                                                 float* __restrict__ als,
                                                 float* __restrict__ ald, int N) {
    const int gw   = (blockIdx.x * 256 + threadIdx.x) >> 6;
    const int lane = threadIdx.x & 63;
    const int r0   = gw * 16;
    if (r0 >= N) return;
    const int m = lane & 15;
    const int q = lane >> 4;

    bf16x8 ah[4], al[4];
    {
        int row = r0 + m;
        if (row >= N) row = N - 1;      // safe clamp; stores are guarded
        const TA* ap = A + (size_t)row * HD;
        #pragma unroll
        for (int ks = 0; ks < 4; ++ks) {
            float vv[8];
            load8(ap + ks * 32 + q * 8, vv);
            #pragma unroll
            for (int j = 0; j < 8; ++j) {
                ushort_t hb, lb;
                bsplit(vv[j], hb, lb);
                ah[ks][j] = (short)hb;
                al[ks][j] = (short)lb;
            }
        }
    }

    float ps[4] = {0,0,0,0};
    float pd[4] = {0,0,0,0};

    #pragma unroll 1
    for (int ct = 0; ct < 8; ++ct) {
        f32x4 acc = {0.f, 0.f, 0.f, 0.f};
        #pragma unroll
        for (int ks = 0; ks < 4; ++ks) {
            bf16x8 wh = *(const bf16x8*)(Whs + ((size_t)(ct * 4 + ks) * 64 + lane) * 8);
            bf16x8 wl = *(const bf16x8*)(Wls + ((size_t)(ct * 4 + ks) * 64 + lane) * 8);
            acc = __builtin_amdgcn_mfma_f32_16x16x32_bf16(ah[ks], wh, acc, 0, 0, 0);
            acc = __builtin_amdgcn_mfma_f32_16x16x32_bf16(al[ks], wh, acc, 0, 0, 0);
            acc = __builtin_amdgcn_mfma_f32_16x16x32_bf16(ah[ks], wl, acc, 0, 0, 0);
        }
        const int col = ct * 16 + m;
        const float asv = a_s[col], adv = a_d[col];
        #pragma unroll
        for (int reg = 0; reg < 4; ++reg) {
            ps[reg] += acc[reg] * asv;
            pd[reg] += acc[reg] * adv;
            int row = r0 + q * 4 + reg;
            if (row < N) h16[(size_t)row * HD + col] = __float2half(acc[reg]);
        }
        if (ct == 3 || ct == 7) {          // head boundary: reduce over m-lanes
            int head = ct >> 2;
            #pragma unroll
            for (int reg = 0; reg < 4; ++reg) {
                float vs = ps[reg], vd = pd[reg];
                for (int o = 8; o >= 1; o >>= 1) {
                    vs += __shfl_xor(vs, o, 64);
                    vd += __shfl_xor(vd, o, 64);
                }
                if (m == 0) {
                    int row = r0 + q * 4 + reg;
                    if (row < N) { als[2 * row + head] = vs; ald[2 * row + head] = vd; }
                }
                ps[reg] = 0.f;  pd[reg] = 0.f;
            }
        }
    }
}

// ---------------- GAT aggregation: one wave per dst node ----------------
// Double-buffered gather groups: issue group b+1's shuffles+loads before
// consuming group b, hiding one memory round-trip per group.
__global__ __launch_bounds__(256) void gat_aggregate(const __half* __restrict__ h,
                                                     const float* __restrict__ als,
                                                     const float* __restrict__ ald,
                                                     const int* __restrict__ indptr,
                                                     const int* __restrict__ csr,
                                                     const float* __restrict__ bias,
                                                     __half* __restrict__ out,
                                                     const float* __restrict__ Wh,
                                                     float* __restrict__ svec, int N) {
    int w    = (blockIdx.x * blockDim.x + threadIdx.x) >> 6;
    int lane = threadIdx.x & 63;
    if (w >= N) return;
    int start = indptr[w], end = indptr[w + 1];
    float ad0 = ald[2 * w], ad1 = ald[2 * w + 1];
    const bool head0 = (lane < 32);
    const int cbase = lane * 2;

    float accx = 0.f, accy = 0.f, d0 = 0.f, d1 = 0.f;
    for (int base = start; base < end; base += 64) {
        int i = base + lane;
        int idx = i < end ? i : end - 1;
        int s = csr[idx];
        unsigned wpack = 0u;
        if (i < end) {
            float2 av = *(const float2*)&als[2 * s];
            float e0 = av.x + ad0;
            float e1 = av.y + ad1;
            e0 = e0 > 0.f ? e0 : NEG_SLOPE * e0;
            e1 = e1 > 0.f ? e1 : NEG_SLOPE * e1;
            __half p0 = __float2half(__expf(e0));
            __half p1 = __float2half(__expf(e1));
            wpack = ((unsigned)__half_as_ushort(p1) << 16) | __half_as_ushort(p0);
            d0 += __half2float(p0);
            d1 += __half2float(p1);
        }
        int nl = end - base; if (nl > 64) nl = 64;
        int nb = (nl + 7) >> 3;

        float waA[8], waB[8];
        __half2 hvA[8], hvB[8];

        auto fetch = [&](int j, float* wa, __half2* hv) {
            int sj[8];
            #pragma unroll
            for (int u = 0; u < 8; ++u) {
                sj[u] = __shfl(s, j + u, 64);
                unsigned wp = (unsigned)__shfl((int)wpack, j + u, 64);
                unsigned bits = head0 ? (wp & 0xffffu) : (wp >> 16);
                wa[u] = __half2float(__ushort_as_half((ushort_t)bits));
            }
            #pragma unroll
            for (int u = 0; u < 8; ++u)
                hv[u] = *(const __half2*)&h[(size_t)sj[u] * HD + cbase];
        };
        auto consume = [&](const float* wa, const __half2* hv) {
            #pragma unroll
            for (int u = 0; u < 8; ++u) {
                float2 f = __half22float2(hv[u]);
                accx += wa[u] * f.x;
                accy += wa[u] * f.y;
            }
        };

        fetch(0, waA, hvA);
        int b = 0;
        for (; b + 1 < nb; ++b) {
            if (b & 1) { fetch((b + 1) * 8, waA, hvA); consume(waB, hvB); }
            else       { fetch((b + 1) * 8, waB, hvB); consume(waA, hvA); }
        }
        if (b & 1) consume(waB, hvB); else consume(waA, hvA);
    }
    for (int o = 32; o >= 1; o >>= 1) {
        d0 += __shfl_xor(d0, o, 64);
        d1 += __shfl_xor(d1, o, 64);
    }
    float D = (head0 ? d0 : d1) + EPSV;
    float ox = accx / D + bias[cbase];
    float oy = accy / D + bias[cbase + 1];
    ox = ox > 0.f ? ox : 0.f;   // ReLU
    oy = oy > 0.f ? oy : 0.f;

    if (svec) {
        float2 wv = *(const float2*)&Wh[cbase];
        float part = ox * wv.x + oy * wv.y;
        for (int o = 32; o >= 1; o >>= 1) part += __shfl_xor(part, o, 64);
        if (lane == 0) svec[w] = part;
    } else {
        *(__half2*)&out[(size_t)w * HD + cbase] =
            __halves2half2(__float2half(ox), __float2half(oy));
    }
}

// ---------------- graph boundaries (batch is sorted) ----------------
__global__ void graph_bounds(const int* __restrict__ batch, int* __restrict__ gstart,
                             int N, int G) {
    int g = blockIdx.x * blockDim.x + threadIdx.x;
    if (g > G) return;
    int lo = 0, hi = N;
    while (lo < hi) {
        int mid = (lo + hi) >> 1;
        if (batch[mid] < g) lo = mid + 1; else hi = mid;
    }
    gstart[g] = lo;
}

// ---------------- per-graph reduce of per-node head dots ----------------
__global__ __launch_bounds__(256) void pool_reduce(const float* __restrict__ s,
                                                   const int* __restrict__ gstart,
                                                   const float* __restrict__ bh,
                                                   float* __restrict__ out, int G) {
    __shared__ float partial[4];
    int g = blockIdx.x, t = threadIdx.x;
    int a = gstart[g], b = gstart[g + 1];
    float sum = 0.f;
    for (int i = a + t; i < b; i += 256) sum += s[i];
    for (int o = 32; o >= 1; o >>= 1) sum += __shfl_xor(sum, o, 64);
    if ((t & 63) == 0) partial[t >> 6] = sum;
    __syncthreads();
    if (t == 0) {
        float cnt = (float)(b - a); if (cnt < 1.f) cnt = 1.f;
        out[g] = (partial[0] + partial[1] + partial[2] + partial[3]) / cnt + bh[0];
    }
}

// ---------------- launch ----------------
extern "C" void kernel_launch(void* const* d_in, const int* in_sizes, int n_in,
                              void* d_out, int out_size, void* d_ws, size_t ws_size,
                              hipStream_t stream) {
    const float* x     = (const float*)d_in[0];
    const int*   ei    = (const int*)d_in[1];
    const int*   batch = (const int*)d_in[2];
    const float* W1  = (const float*)d_in[3];
    const float* as1 = (const float*)d_in[4];
    const float* ad1 = (const float*)d_in[5];
    const float* b1  = (const float*)d_in[6];
    const float* W2  = (const float*)d_in[7];
    const float* as2 = (const float*)d_in[8];
    const float* ad2 = (const float*)d_in[9];
    const float* b2  = (const float*)d_in[10];
    const float* Wh  = (const float*)d_in[11];
    const float* bh  = (const float*)d_in[12];
    float* out = (float*)d_out;

    const int N = in_sizes[0] / HD;
    const int E = in_sizes[1] / 2;
    const int G = out_size;
    const int* srcp = ei;
    const int* dstp = ei + E;
    const int NBK = (N + 255) / 256;      // coarse buckets (dst>>8)
    const int NT  = (E + TILE - 1) / TILE;

    char* ws = (char*)d_ws;
    size_t off = 0;
    auto alloc = [&](size_t bytes) -> void* {
        void* p = ws + off;
        off += (bytes + 255) & ~(size_t)255;
        return p;
    };
    __half* h16   = (__half*)alloc((size_t)N * HD * 2);
    __half* ob16  = (__half*)alloc((size_t)N * HD * 2);
    float* als    = (float*)alloc((size_t)N * 2 * 4);
    float* ald    = (float*)alloc((size_t)N * 2 * 4);
    float* svec   = (float*)alloc((size_t)N * 4);
    int*   indptr = (int*)  alloc((size_t)(N + 1) * 4);
    int*   cnt    = (int*)  alloc((size_t)N * 4);
    int*   bsum   = (int*)  alloc((size_t)NBK * 4);
    int*   csr    = (int*)  alloc((size_t)(E + N) * 4);
    int*   gstart = (int*)  alloc((size_t)(G + 1) * 4);
    int*   tileHist   = (int*)alloc((size_t)NT * 256 * 4);
    int*   bucketBase = (int*)alloc(257 * 4);
    int*   part   = (int*)  alloc((size_t)E * 4);
    ushort_t* Whs1 = (ushort_t*)alloc(16384 * 2);
    ushort_t* Wls1 = (ushort_t*)alloc(16384 * 2);
    ushort_t* Whs2 = (ushort_t*)alloc(16384 * 2);
    ushort_t* Wls2 = (ushort_t*)alloc(16384 * 2);

    // CSR build: partition by dst>>8, then LDS-cursor scatter per bucket
    part_hist<<<NT, 256, 0, stream>>>(dstp, tileHist, E);
    part_offsets<<<1, 256, 0, stream>>>(tileHist, bucketBase, NT);
    part_scatter<<<NT, 256, 0, stream>>>(srcp, dstp, tileHist, part, E);
    fine_counts<<<NBK, 256, 0, stream>>>(part, bucketBase, cnt, bsum, N);
    scan_bsums<<<1, 256, 0, stream>>>(bsum, NBK);
    csr_scatter<<<NBK, 256, 0, stream>>>(part, bucketBase, cnt, bsum, indptr, csr, N);
    graph_bounds<<<1, 64, 0, stream>>>(batch, gstart, N, G);

    // W split+swizzle (tiny)
    split_w<<<64, 256, 0, stream>>>(W1, Whs1, Wls1);
    split_w<<<64, 256, 0, stream>>>(W2, Whs2, Wls2);

    const int nwaves  = (N + 15) / 16;
    const int gblocks = (nwaves + 3) / 4;
    int wgrid = (N * 64 + 255) / 256;

    // layer 1 (logits fused into GEMM epilogue; h stored fp16)
    gemm_mfma<<<gblocks, 256, 0, stream>>>(x, Whs1, Wls1, as1, ad1, h16, als, ald, N);
    gat_aggregate<<<wgrid, 256, 0, stream>>>(h16, als, ald, indptr, csr, b1, ob16,
                                             nullptr, nullptr, N);
    // layer 2 (input fp16)
    gemm_mfma<<<gblocks, 256, 0, stream>>>(ob16, Whs2, Wls2, as2, ad2, h16, als, ald, N);
    gat_aggregate<<<wgrid, 256, 0, stream>>>(h16, als, ald, indptr, csr, b2, nullptr,
                                             Wh, svec, N);
    // pool + head (tiny: 50 blocks x ~1000 scalars)
    pool_reduce<<<G, 256, 0, stream>>>(svec, gstart, bh, out, G);
}

// Round 10
// 254.527 us; speedup vs baseline: 1.0859x; 1.0859x over previous
//
#include <hip/hip_runtime.h>
#include <hip/hip_fp16.h>
#include <math.h>

#define HD 128          // hidden dim (= H*C = D_IN)
#define NEG_SLOPE 0.2f
#define EPSV 1e-16f
#define TILE 8192       // edges per partition tile

typedef unsigned short ushort_t;
typedef __attribute__((ext_vector_type(8))) short bf16x8;
typedef __attribute__((ext_vector_type(4))) float f32x4;

// RNE split of fp32 into hi/lo bf16 bit patterns
__device__ inline void bsplit(float x, ushort_t& hi, ushort_t& lo) {
    unsigned u = __float_as_uint(x);
    unsigned hb = (u + 0x7FFFu + ((u >> 16) & 1u)) >> 16;
    hi = (ushort_t)hb;
    float res = x - __uint_as_float(hb << 16);
    unsigned v = __float_as_uint(res);
    lo = (ushort_t)((v + 0x7FFFu + ((v >> 16) & 1u)) >> 16);
}

// ---------------- edge partition by coarse bucket (dst>>8) ----------------
__global__ __launch_bounds__(256) void part_hist(const int* __restrict__ dst,
                                                 int* __restrict__ tileHist, int E) {
    __shared__ int hist[256];
    int t = threadIdx.x;
    hist[t] = 0;
    __syncthreads();
    int base = blockIdx.x * TILE;
    int end = base + TILE; if (end > E) end = E;
    for (int i = base + t; i < end; i += 256)
        atomicAdd(&hist[dst[i] >> 8], 1);
    __syncthreads();
    tileHist[blockIdx.x * 256 + t] = hist[t];
}

__global__ __launch_bounds__(256) void part_offsets(int* __restrict__ tileHist,
                                                    int* __restrict__ bucketBase,
                                                    int NT) {
    __shared__ int s[256];
    int b = threadIdx.x;
    int total = 0;
    #pragma unroll 8
    for (int t = 0; t < NT; ++t) total += tileHist[t * 256 + b];
    s[b] = total;
    __syncthreads();
    for (int o = 1; o < 256; o <<= 1) {
        int v = (b >= o) ? s[b - o] : 0;
        __syncthreads();
        s[b] += v;
        __syncthreads();
    }
    int base = (b == 0) ? 0 : s[b - 1];
    bucketBase[b] = base;
    if (b == 255) bucketBase[256] = s[255];
    int run = base;
    #pragma unroll 8
    for (int t = 0; t < NT; ++t) {
        int v = tileHist[t * 256 + b];
        tileHist[t * 256 + b] = run;
        run += v;
    }
}

// packed entry: (src<<8) | (dst&255)
__global__ __launch_bounds__(256) void part_scatter(const int* __restrict__ src,
                                                    const int* __restrict__ dst,
                                                    const int* __restrict__ tileHist,
                                                    int* __restrict__ part, int E) {
    __shared__ int cur[256];
    int t = threadIdx.x;
    cur[t] = tileHist[blockIdx.x * 256 + t];
    __syncthreads();
    int base = blockIdx.x * TILE;
    int end = base + TILE; if (end > E) end = E;
    for (int i = base + t; i < end; i += 256) {
        int d = dst[i], s = src[i];
        int p = atomicAdd(&cur[d >> 8], 1);
        part[p] = (s << 8) | (d & 255);
    }
}

// per-node counts (+1 self-loop) AND per-bucket scan input
__global__ __launch_bounds__(256) void fine_counts(const int* __restrict__ part,
                                                   const int* __restrict__ bucketBase,
                                                   int* __restrict__ cnt,
                                                   int* __restrict__ bsum, int N) {
    __shared__ int hist[256];
    int t = threadIdx.x;
    hist[t] = 0;
    __syncthreads();
    int b = blockIdx.x;
    int s0 = bucketBase[b], s1 = bucketBase[b + 1];
    for (int i = s0 + t; i < s1; i += 256)
        atomicAdd(&hist[part[i] & 255], 1);
    __syncthreads();
    int d = b * 256 + t;
    if (d < N) cnt[d] = hist[t] + 1;
    if (t == 0) {
        int nn = N - b * 256; if (nn > 256) nn = 256; if (nn < 0) nn = 0;
        bsum[b] = (s1 - s0) + nn;   // edges in bucket + self-loops
    }
}

// exclusive scan of per-bucket sums (single block, tiles of 256 w/ carry)
__global__ __launch_bounds__(256) void scan_bsums(int* __restrict__ bsum, int NB) {
    __shared__ int s[256];
    __shared__ int carry;
    int t = threadIdx.x;
    if (t == 0) carry = 0;
    __syncthreads();
    for (int base = 0; base < NB; base += 256) {
        int i = base + t;
        int v = (i < NB) ? bsum[i] : 0;
        s[t] = v;
        __syncthreads();
        for (int o = 1; o < 256; o <<= 1) {
            int u = (t >= o) ? s[t - o] : 0;
            __syncthreads();
            s[t] += u;
            __syncthreads();
        }
        int excl = ((t == 0) ? 0 : s[t - 1]) + carry;
        if (i < NB) bsum[i] = excl;
        __syncthreads();
        if (t == 0) carry += s[255];
        __syncthreads();
    }
}

// CSR scatter: in-block exclusive scan of cnt -> indptr + LDS cursors, then scatter
__global__ __launch_bounds__(256) void csr_scatter(const int* __restrict__ part,
                                                   const int* __restrict__ bucketBase,
                                                   const int* __restrict__ cnt,
                                                   const int* __restrict__ bsum,
                                                   int* __restrict__ indptr,
                                                   int* __restrict__ csr, int N) {
    __shared__ int s[256];
    __shared__ int cur[256];
    int t = threadIdx.x;
    int b = blockIdx.x;
    int d = b * 256 + t;
    int v = (d < N) ? cnt[d] : 0;
    s[t] = v;
    __syncthreads();
    for (int o = 1; o < 256; o <<= 1) {
        int u = (t >= o) ? s[t - o] : 0;
        __syncthreads();
        s[t] += u;
        __syncthreads();
    }
    int excl = ((t == 0) ? 0 : s[t - 1]) + bsum[b];
    if (d < N) indptr[d] = excl;
    if (d == N - 1) indptr[N] = excl + v;
    cur[t] = excl;
    __syncthreads();
    int s0 = bucketBase[b], s1 = bucketBase[b + 1];
    for (int i = s0 + t; i < s1; i += 256) {
        int e = part[i];
        int p = atomicAdd(&cur[e & 255], 1);
        csr[p] = e >> 8;
    }
    __syncthreads();
    if (d < N) csr[cur[t]] = d;   // self-loop fills the one remaining slot
}

// ---------------- W split+swizzle into MFMA B-fragment order ----------------
__global__ __launch_bounds__(256) void split_w(const float* __restrict__ W,
                                               ushort_t* __restrict__ Whs,
                                               ushort_t* __restrict__ Wls) {
    int idx = blockIdx.x * 256 + threadIdx.x;   // 0..16383
    int j    = idx & 7;
    int lane = (idx >> 3) & 63;
    int ks   = (idx >> 9) & 3;
    int ct   = idx >> 11;
    int n = ct * 16 + (lane & 15);
    int k = ks * 32 + (lane >> 4) * 8 + j;
    ushort_t hi, lo;
    bsplit(W[k * 128 + n], hi, lo);
    Whs[idx] = hi;
    Wls[idx] = lo;
}

// ---------------- A-row 8-element loaders (fp32 or fp16 input) ----------------
__device__ inline void load8(const float* p, float* vv) {
    float4 a = *(const float4*)p;
    float4 b = *(const float4*)(p + 4);
    vv[0]=a.x; vv[1]=a.y; vv[2]=a.z; vv[3]=a.w;
    vv[4]=b.x; vv[5]=b.y; vv[6]=b.z; vv[7]=b.w;
}
__device__ inline void load8(const __half* p, float* vv) {
    bf16x8 r = *(const bf16x8*)p;
    #pragma unroll
    for (int j = 0; j < 8; ++j)
        vv[j] = __half2float(__ushort_as_half((ushort_t)r[j]));
}

// ---------------- GEMM via split-bf16 MFMA + fused attention logits ----------------
template <typename TA>
__global__ __launch_bounds__(256) void gemm_mfma(const TA* __restrict__ A,
                                                 const ushort_t* __restrict__ Whs,
                                                 const ushort_t* __restrict__ Wls,
                                                 const float* __restrict__ a_s,
                                                 const float* __restrict__ a_d,
                                                 __half* __restrict__ h16,
                                                 float* __restrict__ als,
                                                 float* __restrict__ ald, int N) {
    const int gw   = (blockIdx.x * 256 + threadIdx.x) >> 6;
    const int lane = threadIdx.x & 63;
    const int r0   = gw * 16;
    if (r0 >= N) return;
    const int m = lane & 15;
    const int q = lane >> 4;

    bf16x8 ah[4], al[4];
    {
        int row = r0 + m;
        if (row >= N) row = N - 1;      // safe clamp; stores are guarded
        const TA* ap = A + (size_t)row * HD;
        #pragma unroll
        for (int ks = 0; ks < 4; ++ks) {
            float vv[8];
            load8(ap + ks * 32 + q * 8, vv);
            #pragma unroll
            for (int j = 0; j < 8; ++j) {
                ushort_t hb, lb;
                bsplit(vv[j], hb, lb);
                ah[ks][j] = (short)hb;
                al[ks][j] = (short)lb;
            }
        }
    }

    float ps[4] = {0,0,0,0};
    float pd[4] = {0,0,0,0};

    #pragma unroll 1
    for (int ct = 0; ct < 8; ++ct) {
        f32x4 acc = {0.f, 0.f, 0.f, 0.f};
        #pragma unroll
        for (int ks = 0; ks < 4; ++ks) {
            bf16x8 wh = *(const bf16x8*)(Whs + ((size_t)(ct * 4 + ks) * 64 + lane) * 8);
            bf16x8 wl = *(const bf16x8*)(Wls + ((size_t)(ct * 4 + ks) * 64 + lane) * 8);
            acc = __builtin_amdgcn_mfma_f32_16x16x32_bf16(ah[ks], wh, acc, 0, 0, 0);
            acc = __builtin_amdgcn_mfma_f32_16x16x32_bf16(al[ks], wh, acc, 0, 0, 0);
            acc = __builtin_amdgcn_mfma_f32_16x16x32_bf16(ah[ks], wl, acc, 0, 0, 0);
        }
        const int col = ct * 16 + m;
        const float asv = a_s[col], adv = a_d[col];
        #pragma unroll
        for (int reg = 0; reg < 4; ++reg) {
            ps[reg] += acc[reg] * asv;
            pd[reg] += acc[reg] * adv;
            int row = r0 + q * 4 + reg;
            if (row < N) h16[(size_t)row * HD + col] = __float2half(acc[reg]);
        }
        if (ct == 3 || ct == 7) {          // head boundary: reduce over m-lanes
            int head = ct >> 2;
            #pragma unroll
            for (int reg = 0; reg < 4; ++reg) {
                float vs = ps[reg], vd = pd[reg];
                for (int o = 8; o >= 1; o >>= 1) {
                    vs += __shfl_xor(vs, o, 64);
                    vd += __shfl_xor(vd, o, 64);
                }
                if (m == 0) {
                    int row = r0 + q * 4 + reg;
                    if (row < N) { als[2 * row + head] = vs; ald[2 * row + head] = vd; }
                }
                ps[reg] = 0.f;  pd[reg] = 0.f;
            }
        }
    }
}

// ---------------- GAT aggregation: one wave per dst node ----------------
// Per-wave LDS strip holds (src, packed fp16 weights) per edge: 1 ds_write_b64
// per 64 edges, then 1 broadcast ds_read_b64 per edge (replaces 2 bpermutes).
__global__ __launch_bounds__(256) void gat_aggregate(const __half* __restrict__ h,
                                                     const float* __restrict__ als,
                                                     const float* __restrict__ ald,
                                                     const int* __restrict__ indptr,
                                                     const int* __restrict__ csr,
                                                     const float* __restrict__ bias,
                                                     __half* __restrict__ out,
                                                     const float* __restrict__ Wh,
                                                     float* __restrict__ svec, int N) {
    __shared__ int2 ebuf[4][64];       // per-wave strip (wave-private, no barrier)
    int w    = (blockIdx.x * blockDim.x + threadIdx.x) >> 6;
    int lane = threadIdx.x & 63;
    int wv   = (threadIdx.x >> 6);
    if (w >= N) return;
    int start = indptr[w], end = indptr[w + 1];
    float ad0 = ald[2 * w], ad1 = ald[2 * w + 1];
    const bool head0 = (lane < 32);
    const int cbase = lane * 2;

    float accx = 0.f, accy = 0.f, d0 = 0.f, d1 = 0.f;
    for (int base = start; base < end; base += 64) {
        int i = base + lane;
        int idx = i < end ? i : end - 1;
        int s = csr[idx];
        unsigned wpack = 0u;
        if (i < end) {
            float2 av = *(const float2*)&als[2 * s];
            float e0 = av.x + ad0;
            float e1 = av.y + ad1;
            e0 = e0 > 0.f ? e0 : NEG_SLOPE * e0;
            e1 = e1 > 0.f ? e1 : NEG_SLOPE * e1;
            __half p0 = __float2half(__expf(e0));
            __half p1 = __float2half(__expf(e1));
            wpack = ((unsigned)__half_as_ushort(p1) << 16) | __half_as_ushort(p0);
            d0 += __half2float(p0);
            d1 += __half2float(p1);
        }
        ebuf[wv][lane] = make_int2(s, (int)wpack);   // intra-wave RAW: lgkmcnt-ordered
        int nl = end - base; if (nl > 64) nl = 64;
        int nb = (nl + 7) >> 3;
        for (int b = 0; b < nb; ++b) {
            int j = b * 8;
            int2 e[8];
            #pragma unroll
            for (int u = 0; u < 8; ++u) e[u] = ebuf[wv][j + u];   // broadcast reads
            float wa[8];
            #pragma unroll
            for (int u = 0; u < 8; ++u) {
                unsigned wp = (unsigned)e[u].y;
                unsigned bits = head0 ? (wp & 0xffffu) : (wp >> 16);
                wa[u] = __half2float(__ushort_as_half((ushort_t)bits));
            }
            __half2 hv[8];
            #pragma unroll
            for (int u = 0; u < 8; ++u)
                hv[u] = *(const __half2*)&h[(size_t)e[u].x * HD + cbase];
            #pragma unroll
            for (int u = 0; u < 8; ++u) {
                float2 f = __half22float2(hv[u]);
                accx += wa[u] * f.x;
                accy += wa[u] * f.y;
            }
        }
    }
    for (int o = 32; o >= 1; o >>= 1) {
        d0 += __shfl_xor(d0, o, 64);
        d1 += __shfl_xor(d1, o, 64);
    }
    float D = (head0 ? d0 : d1) + EPSV;
    float ox = accx / D + bias[cbase];
    float oy = accy / D + bias[cbase + 1];
    ox = ox > 0.f ? ox : 0.f;   // ReLU
    oy = oy > 0.f ? oy : 0.f;

    if (svec) {
        float2 wv2 = *(const float2*)&Wh[cbase];
        float part = ox * wv2.x + oy * wv2.y;
        for (int o = 32; o >= 1; o >>= 1) part += __shfl_xor(part, o, 64);
        if (lane == 0) svec[w] = part;
    } else {
        *(__half2*)&out[(size_t)w * HD + cbase] =
            __halves2half2(__float2half(ox), __float2half(oy));
    }
}

// ---------------- graph boundaries (batch is sorted) ----------------
__global__ void graph_bounds(const int* __restrict__ batch, int* __restrict__ gstart,
                             int N, int G) {
    int g = blockIdx.x * blockDim.x + threadIdx.x;
    if (g > G) return;
    int lo = 0, hi = N;
    while (lo < hi) {
        int mid = (lo + hi) >> 1;
        if (batch[mid] < g) lo = mid + 1; else hi = mid;
    }
    gstart[g] = lo;
}

// ---------------- per-graph reduce of per-node head dots ----------------
__global__ __launch_bounds__(256) void pool_reduce(const float* __restrict__ s,
                                                   const int* __restrict__ gstart,
                                                   const float* __restrict__ bh,
                                                   float* __restrict__ out, int G) {
    __shared__ float partial[4];
    int g = blockIdx.x, t = threadIdx.x;
    int a = gstart[g], b = gstart[g + 1];
    float sum = 0.f;
    for (int i = a + t; i < b; i += 256) sum += s[i];
    for (int o = 32; o >= 1; o >>= 1) sum += __shfl_xor(sum, o, 64);
    if ((t & 63) == 0) partial[t >> 6] = sum;
    __syncthreads();
    if (t == 0) {
        float cnt = (float)(b - a); if (cnt < 1.f) cnt = 1.f;
        out[g] = (partial[0] + partial[1] + partial[2] + partial[3]) / cnt + bh[0];
    }
}

// ---------------- launch ----------------
extern "C" void kernel_launch(void* const* d_in, const int* in_sizes, int n_in,
                              void* d_out, int out_size, void* d_ws, size_t ws_size,
                              hipStream_t stream) {
    const float* x     = (const float*)d_in[0];
    const int*   ei    = (const int*)d_in[1];
    const int*   batch = (const int*)d_in[2];
    const float* W1  = (const float*)d_in[3];
    const float* as1 = (const float*)d_in[4];
    const float* ad1 = (const float*)d_in[5];
    const float* b1  = (const float*)d_in[6];
    const float* W2  = (const float*)d_in[7];
    const float* as2 = (const float*)d_in[8];
    const float* ad2 = (const float*)d_in[9];
    const float* b2  = (const float*)d_in[10];
    const float* Wh  = (const float*)d_in[11];
    const float* bh  = (const float*)d_in[12];
    float* out = (float*)d_out;

    const int N = in_sizes[0] / HD;
    const int E = in_sizes[1] / 2;
    const int G = out_size;
    const int* srcp = ei;
    const int* dstp = ei + E;
    const int NBK = (N + 255) / 256;      // coarse buckets (dst>>8)
    const int NT  = (E + TILE - 1) / TILE;

    char* ws = (char*)d_ws;
    size_t off = 0;
    auto alloc = [&](size_t bytes) -> void* {
        void* p = ws + off;
        off += (bytes + 255) & ~(size_t)255;
        return p;
    };
    __half* h16   = (__half*)alloc((size_t)N * HD * 2);
    __half* ob16  = (__half*)alloc((size_t)N * HD * 2);
    float* als    = (float*)alloc((size_t)N * 2 * 4);
    float* ald    = (float*)alloc((size_t)N * 2 * 4);
    float* svec   = (float*)alloc((size_t)N * 4);
    int*   indptr = (int*)  alloc((size_t)(N + 1) * 4);
    int*   cnt    = (int*)  alloc((size_t)N * 4);
    int*   bsum   = (int*)  alloc((size_t)NBK * 4);
    int*   csr    = (int*)  alloc((size_t)(E + N) * 4);
    int*   gstart = (int*)  alloc((size_t)(G + 1) * 4);
    int*   tileHist   = (int*)alloc((size_t)NT * 256 * 4);
    int*   bucketBase = (int*)alloc(257 * 4);
    int*   part   = (int*)  alloc((size_t)E * 4);
    ushort_t* Whs1 = (ushort_t*)alloc(16384 * 2);
    ushort_t* Wls1 = (ushort_t*)alloc(16384 * 2);
    ushort_t* Whs2 = (ushort_t*)alloc(16384 * 2);
    ushort_t* Wls2 = (ushort_t*)alloc(16384 * 2);

    // CSR build: partition by dst>>8, then LDS-cursor scatter per bucket
    part_hist<<<NT, 256, 0, stream>>>(dstp, tileHist, E);
    part_offsets<<<1, 256, 0, stream>>>(tileHist, bucketBase, NT);
    part_scatter<<<NT, 256, 0, stream>>>(srcp, dstp, tileHist, part, E);
    fine_counts<<<NBK, 256, 0, stream>>>(part, bucketBase, cnt, bsum, N);
    scan_bsums<<<1, 256, 0, stream>>>(bsum, NBK);
    csr_scatter<<<NBK, 256, 0, stream>>>(part, bucketBase, cnt, bsum, indptr, csr, N);
    graph_bounds<<<1, 64, 0, stream>>>(batch, gstart, N, G);

    // W split+swizzle (tiny)
    split_w<<<64, 256, 0, stream>>>(W1, Whs1, Wls1);
    split_w<<<64, 256, 0, stream>>>(W2, Whs2, Wls2);

    const int nwaves  = (N + 15) / 16;
    const int gblocks = (nwaves + 3) / 4;
    int wgrid = (N * 64 + 255) / 256;

    // layer 1 (logits fused into GEMM epilogue; h stored fp16)
    gemm_mfma<<<gblocks, 256, 0, stream>>>(x, Whs1, Wls1, as1, ad1, h16, als, ald, N);
    gat_aggregate<<<wgrid, 256, 0, stream>>>(h16, als, ald, indptr, csr, b1, ob16,
                                             nullptr, nullptr, N);
    // layer 2 (input fp16)
    gemm_mfma<<<gblocks, 256, 0, stream>>>(ob16, Whs2, Wls2, as2, ad2, h16, als, ald, N);
    gat_aggregate<<<wgrid, 256, 0, stream>>>(h16, als, ald, indptr, csr, b2, nullptr,
                                             Wh, svec, N);
    // pool + head (tiny: 50 blocks x ~1000 scalars)
    pool_reduce<<<G, 256, 0, stream>>>(svec, gstart, bh, out, G);
}

// Round 11
// 247.205 us; speedup vs baseline: 1.1181x; 1.0296x over previous
//
#include <hip/hip_runtime.h>
#include <hip/hip_fp16.h>
#include <math.h>

#define HD 128          // hidden dim (= H*C = D_IN)
#define NEG_SLOPE 0.2f
#define EPSV 1e-16f
#define TILE 8192       // edges per partition tile

typedef unsigned short ushort_t;
typedef __attribute__((ext_vector_type(8))) short bf16x8;
typedef __attribute__((ext_vector_type(8))) _Float16 f16x8;
typedef __attribute__((ext_vector_type(4))) float f32x4;

// RNE split of fp32 into hi/lo bf16 bit patterns
__device__ inline void bsplit(float x, ushort_t& hi, ushort_t& lo) {
    unsigned u = __float_as_uint(x);
    unsigned hb = (u + 0x7FFFu + ((u >> 16) & 1u)) >> 16;
    hi = (ushort_t)hb;
    float res = x - __uint_as_float(hb << 16);
    unsigned v = __float_as_uint(res);
    lo = (ushort_t)((v + 0x7FFFu + ((v >> 16) & 1u)) >> 16);
}

// ---------------- edge partition by coarse bucket (dst>>8) ----------------
__global__ __launch_bounds__(256) void part_hist(const int* __restrict__ dst,
                                                 int* __restrict__ tileHist, int E) {
    __shared__ int hist[256];
    int t = threadIdx.x;
    hist[t] = 0;
    __syncthreads();
    int base = blockIdx.x * TILE;
    int end = base + TILE; if (end > E) end = E;
    for (int i = base + t; i < end; i += 256)
        atomicAdd(&hist[dst[i] >> 8], 1);
    __syncthreads();
    tileHist[blockIdx.x * 256 + t] = hist[t];
}

__global__ __launch_bounds__(256) void part_offsets(int* __restrict__ tileHist,
                                                    int* __restrict__ bucketBase,
                                                    int NT) {
    __shared__ int s[256];
    int b = threadIdx.x;
    int total = 0;
    #pragma unroll 8
    for (int t = 0; t < NT; ++t) total += tileHist[t * 256 + b];
    s[b] = total;
    __syncthreads();
    for (int o = 1; o < 256; o <<= 1) {
        int v = (b >= o) ? s[b - o] : 0;
        __syncthreads();
        s[b] += v;
        __syncthreads();
    }
    int base = (b == 0) ? 0 : s[b - 1];
    bucketBase[b] = base;
    if (b == 255) bucketBase[256] = s[255];
    int run = base;
    #pragma unroll 8
    for (int t = 0; t < NT; ++t) {
        int v = tileHist[t * 256 + b];
        tileHist[t * 256 + b] = run;
        run += v;
    }
}

// packed entry: (src<<8) | (dst&255)
__global__ __launch_bounds__(256) void part_scatter(const int* __restrict__ src,
                                                    const int* __restrict__ dst,
                                                    const int* __restrict__ tileHist,
                                                    int* __restrict__ part, int E) {
    __shared__ int cur[256];
    int t = threadIdx.x;
    cur[t] = tileHist[blockIdx.x * 256 + t];
    __syncthreads();
    int base = blockIdx.x * TILE;
    int end = base + TILE; if (end > E) end = E;
    for (int i = base + t; i < end; i += 256) {
        int d = dst[i], s = src[i];
        int p = atomicAdd(&cur[d >> 8], 1);
        part[p] = (s << 8) | (d & 255);
    }
}

// Fused CSR build: per-bucket histogram -> LDS scan -> indptr (closed form:
// indptr[d] = bucketBase[b] + in-bucket-prefix + d, since each node adds
// exactly one self-loop) -> LDS-cursor scatter -> self-loop fill.
__global__ __launch_bounds__(256) void csr_build(const int* __restrict__ part,
                                                 const int* __restrict__ bucketBase,
                                                 int* __restrict__ indptr,
                                                 int* __restrict__ csr, int N, int E) {
    __shared__ int hist[256];
    __shared__ int pfx[256];
    __shared__ int cur[256];
    int t = threadIdx.x;
    int b = blockIdx.x;
    hist[t] = 0;
    __syncthreads();
    int s0 = bucketBase[b], s1 = bucketBase[b + 1];
    for (int i = s0 + t; i < s1; i += 256)
        atomicAdd(&hist[part[i] & 255], 1);
    __syncthreads();
    pfx[t] = hist[t];
    __syncthreads();
    for (int o = 1; o < 256; o <<= 1) {
        int u = (t >= o) ? pfx[t - o] : 0;
        __syncthreads();
        pfx[t] += u;
        __syncthreads();
    }
    int excl = (t == 0) ? 0 : pfx[t - 1];
    int d = b * 256 + t;
    int ip = s0 + excl + d;            // edges before d + self-loops before d
    if (d < N) indptr[d] = ip;
    if (b == 0 && t == 0) indptr[N] = E + N;
    cur[t] = ip;
    __syncthreads();
    for (int i = s0 + t; i < s1; i += 256) {
        int e = part[i];
        int p = atomicAdd(&cur[e & 255], 1);
        csr[p] = e >> 8;
    }
    __syncthreads();
    if (d < N) csr[cur[t]] = d;        // self-loop fills the one remaining slot
}

// ---------------- W split+swizzle (both layers in one launch) ----------------
// blocks 0..63: layer-1 bf16 hi/lo split; blocks 64..127: layer-2 fp16 hi/lo.
// flat idx = ((ct*4 + ks)*64 + lane)*8 + j ; value = W[k][n],
// n = ct*16 + (lane&15), k = ks*32 + (lane>>4)*8 + j
__global__ __launch_bounds__(256) void split_w(const float* __restrict__ W1,
                                               const float* __restrict__ W2,
                                               ushort_t* __restrict__ Whs1,
                                               ushort_t* __restrict__ Wls1,
                                               ushort_t* __restrict__ Whs2,
                                               ushort_t* __restrict__ Wls2) {
    int blk = blockIdx.x & 63;
    bool layer2 = blockIdx.x >= 64;
    int idx = blk * 256 + threadIdx.x;   // 0..16383
    int j    = idx & 7;
    int lane = (idx >> 3) & 63;
    int ks   = (idx >> 9) & 3;
    int ct   = idx >> 11;
    int n = ct * 16 + (lane & 15);
    int k = ks * 32 + (lane >> 4) * 8 + j;
    if (!layer2) {
        ushort_t hi, lo;
        bsplit(W1[k * 128 + n], hi, lo);
        Whs1[idx] = hi;
        Wls1[idx] = lo;
    } else {
        float v = W2[k * 128 + n];
        __half h = __float2half(v);
        __half l = __float2half(v - __half2float(h));
        Whs2[idx] = __half_as_ushort(h);
        Wls2[idx] = __half_as_ushort(l);
    }
}

// ---------------- layer-1 GEMM: split-bf16 MFMA + fused attention logits ----------------
__global__ __launch_bounds__(256) void gemm_mfma(const float* __restrict__ A,
                                                 const ushort_t* __restrict__ Whs,
                                                 const ushort_t* __restrict__ Wls,
                                                 const float* __restrict__ a_s,
                                                 const float* __restrict__ a_d,
                                                 __half* __restrict__ h16,
                                                 float* __restrict__ als,
                                                 float* __restrict__ ald, int N) {
    const int gw   = (blockIdx.x * 256 + threadIdx.x) >> 6;
    const int lane = threadIdx.x & 63;
    const int r0   = gw * 16;
    if (r0 >= N) return;
    const int m = lane & 15;
    const int q = lane >> 4;

    bf16x8 ah[4], al[4];
    {
        int row = r0 + m;
        if (row >= N) row = N - 1;      // safe clamp; stores are guarded
        const float* ap = A + (size_t)row * HD;
        #pragma unroll
        for (int ks = 0; ks < 4; ++ks) {
            float4 v0 = *(const float4*)(ap + ks * 32 + q * 8);
            float4 v1 = *(const float4*)(ap + ks * 32 + q * 8 + 4);
            float vv[8] = {v0.x, v0.y, v0.z, v0.w, v1.x, v1.y, v1.z, v1.w};
            #pragma unroll
            for (int j = 0; j < 8; ++j) {
                ushort_t hb, lb;
                bsplit(vv[j], hb, lb);
                ah[ks][j] = (short)hb;
                al[ks][j] = (short)lb;
            }
        }
    }

    float ps[4] = {0,0,0,0};
    float pd[4] = {0,0,0,0};

    #pragma unroll 1
    for (int ct = 0; ct < 8; ++ct) {
        f32x4 acc = {0.f, 0.f, 0.f, 0.f};
        #pragma unroll
        for (int ks = 0; ks < 4; ++ks) {
            bf16x8 wh = *(const bf16x8*)(Whs + ((size_t)(ct * 4 + ks) * 64 + lane) * 8);
            bf16x8 wl = *(const bf16x8*)(Wls + ((size_t)(ct * 4 + ks) * 64 + lane) * 8);
            acc = __builtin_amdgcn_mfma_f32_16x16x32_bf16(ah[ks], wh, acc, 0, 0, 0);
            acc = __builtin_amdgcn_mfma_f32_16x16x32_bf16(al[ks], wh, acc, 0, 0, 0);
            acc = __builtin_amdgcn_mfma_f32_16x16x32_bf16(ah[ks], wl, acc, 0, 0, 0);
        }
        const int col = ct * 16 + m;
        const float asv = a_s[col], adv = a_d[col];
        #pragma unroll
        for (int reg = 0; reg < 4; ++reg) {
            ps[reg] += acc[reg] * asv;
            pd[reg] += acc[reg] * adv;
            int row = r0 + q * 4 + reg;
            if (row < N) h16[(size_t)row * HD + col] = __float2half(acc[reg]);
        }
        if (ct == 3 || ct == 7) {          // head boundary: reduce over m-lanes
            int head = ct >> 2;
            #pragma unroll
            for (int reg = 0; reg < 4; ++reg) {
                float vs = ps[reg], vd = pd[reg];
                for (int o = 8; o >= 1; o >>= 1) {
                    vs += __shfl_xor(vs, o, 64);
                    vd += __shfl_xor(vd, o, 64);
                }
                if (m == 0) {
                    int row = r0 + q * 4 + reg;
                    if (row < N) { als[2 * row + head] = vs; ald[2 * row + head] = vd; }
                }
                ps[reg] = 0.f;  pd[reg] = 0.f;
            }
        }
    }
}

// ---------------- layer-2 GEMM: native f16 MFMA (A exact fp16, W 2-term) ----------------
__global__ __launch_bounds__(256) void gemm_mfma_f16(const __half* __restrict__ A,
                                                     const ushort_t* __restrict__ Whs,
                                                     const ushort_t* __restrict__ Wls,
                                                     const float* __restrict__ a_s,
                                                     const float* __restrict__ a_d,
                                                     __half* __restrict__ h16,
                                                     float* __restrict__ als,
                                                     float* __restrict__ ald, int N) {
    const int gw   = (blockIdx.x * 256 + threadIdx.x) >> 6;
    const int lane = threadIdx.x & 63;
    const int r0   = gw * 16;
    if (r0 >= N) return;
    const int m = lane & 15;
    const int q = lane >> 4;

    f16x8 ah[4];
    {
        int row = r0 + m;
        if (row >= N) row = N - 1;
        const __half* ap = A + (size_t)row * HD;
        #pragma unroll
        for (int ks = 0; ks < 4; ++ks)
            ah[ks] = *(const f16x8*)(ap + ks * 32 + q * 8);
    }

    float ps[4] = {0,0,0,0};
    float pd[4] = {0,0,0,0};

    #pragma unroll 1
    for (int ct = 0; ct < 8; ++ct) {
        f32x4 acc = {0.f, 0.f, 0.f, 0.f};
        #pragma unroll
        for (int ks = 0; ks < 4; ++ks) {
            f16x8 wh = *(const f16x8*)(Whs + ((size_t)(ct * 4 + ks) * 64 + lane) * 8);
            f16x8 wl = *(const f16x8*)(Wls + ((size_t)(ct * 4 + ks) * 64 + lane) * 8);
            acc = __builtin_amdgcn_mfma_f32_16x16x32_f16(ah[ks], wh, acc, 0, 0, 0);
            acc = __builtin_amdgcn_mfma_f32_16x16x32_f16(ah[ks], wl, acc, 0, 0, 0);
        }
        const int col = ct * 16 + m;
        const float asv = a_s[col], adv = a_d[col];
        #pragma unroll
        for (int reg = 0; reg < 4; ++reg) {
            ps[reg] += acc[reg] * asv;
            pd[reg] += acc[reg] * adv;
            int row = r0 + q * 4 + reg;
            if (row < N) h16[(size_t)row * HD + col] = __float2half(acc[reg]);
        }
        if (ct == 3 || ct == 7) {
            int head = ct >> 2;
            #pragma unroll
            for (int reg = 0; reg < 4; ++reg) {
                float vs = ps[reg], vd = pd[reg];
                for (int o = 8; o >= 1; o >>= 1) {
                    vs += __shfl_xor(vs, o, 64);
                    vd += __shfl_xor(vd, o, 64);
                }
                if (m == 0) {
                    int row = r0 + q * 4 + reg;
                    if (row < N) { als[2 * row + head] = vs; ald[2 * row + head] = vd; }
                }
                ps[reg] = 0.f;  pd[reg] = 0.f;
            }
        }
    }
}

// ---------------- GAT aggregation: one wave per dst node ----------------
// Per-wave LDS strip: 1 ds_write_b64 per 64 edges, 1 broadcast ds_read_b64/edge.
__global__ __launch_bounds__(256) void gat_aggregate(const __half* __restrict__ h,
                                                     const float* __restrict__ als,
                                                     const float* __restrict__ ald,
                                                     const int* __restrict__ indptr,
                                                     const int* __restrict__ csr,
                                                     const float* __restrict__ bias,
                                                     __half* __restrict__ out,
                                                     const float* __restrict__ Wh,
                                                     float* __restrict__ svec, int N) {
    __shared__ int2 ebuf[4][64];       // per-wave strip (wave-private, no barrier)
    int w    = (blockIdx.x * blockDim.x + threadIdx.x) >> 6;
    int lane = threadIdx.x & 63;
    int wv   = (threadIdx.x >> 6);
    if (w >= N) return;
    int start = indptr[w], end = indptr[w + 1];
    float ad0 = ald[2 * w], ad1 = ald[2 * w + 1];
    const bool head0 = (lane < 32);
    const int cbase = lane * 2;

    float accx = 0.f, accy = 0.f, d0 = 0.f, d1 = 0.f;
    for (int base = start; base < end; base += 64) {
        int i = base + lane;
        int idx = i < end ? i : end - 1;
        int s = csr[idx];
        unsigned wpack = 0u;
        if (i < end) {
            float2 av = *(const float2*)&als[2 * s];
            float e0 = av.x + ad0;
            float e1 = av.y + ad1;
            e0 = e0 > 0.f ? e0 : NEG_SLOPE * e0;
            e1 = e1 > 0.f ? e1 : NEG_SLOPE * e1;
            __half p0 = __float2half(__expf(e0));
            __half p1 = __float2half(__expf(e1));
            wpack = ((unsigned)__half_as_ushort(p1) << 16) | __half_as_ushort(p0);
            d0 += __half2float(p0);
            d1 += __half2float(p1);
        }
        ebuf[wv][lane] = make_int2(s, (int)wpack);   // intra-wave RAW: lgkmcnt-ordered
        int nl = end - base; if (nl > 64) nl = 64;
        int nb = (nl + 7) >> 3;
        for (int b = 0; b < nb; ++b) {
            int j = b * 8;
            int2 e[8];
            #pragma unroll
            for (int u = 0; u < 8; ++u) e[u] = ebuf[wv][j + u];   // broadcast reads
            float wa[8];
            #pragma unroll
            for (int u = 0; u < 8; ++u) {
                unsigned wp = (unsigned)e[u].y;
                unsigned bits = head0 ? (wp & 0xffffu) : (wp >> 16);
                wa[u] = __half2float(__ushort_as_half((ushort_t)bits));
            }
            __half2 hv[8];
            #pragma unroll
            for (int u = 0; u < 8; ++u)
                hv[u] = *(const __half2*)&h[(size_t)e[u].x * HD + cbase];
            #pragma unroll
            for (int u = 0; u < 8; ++u) {
                float2 f = __half22float2(hv[u]);
                accx += wa[u] * f.x;
                accy += wa[u] * f.y;
            }
        }
    }
    for (int o = 32; o >= 1; o >>= 1) {
        d0 += __shfl_xor(d0, o, 64);
        d1 += __shfl_xor(d1, o, 64);
    }
    float D = (head0 ? d0 : d1) + EPSV;
    float ox = accx / D + bias[cbase];
    float oy = accy / D + bias[cbase + 1];
    ox = ox > 0.f ? ox : 0.f;   // ReLU
    oy = oy > 0.f ? oy : 0.f;

    if (svec) {
        float2 wv2 = *(const float2*)&Wh[cbase];
        float part = ox * wv2.x + oy * wv2.y;
        for (int o = 32; o >= 1; o >>= 1) part += __shfl_xor(part, o, 64);
        if (lane == 0) svec[w] = part;
    } else {
        *(__half2*)&out[(size_t)w * HD + cbase] =
            __halves2half2(__float2half(ox), __float2half(oy));
    }
}

// ---------------- mean pool + head (inline graph-bound binary search) ----------------
__global__ __launch_bounds__(256) void pool_head(const float* __restrict__ s,
                                                 const int* __restrict__ batch,
                                                 const float* __restrict__ bh,
                                                 float* __restrict__ out, int N, int G) {
    __shared__ float partial[4];
    int g = blockIdx.x, t = threadIdx.x;
    auto lb = [&](int key) {
        int lo = 0, hi = N;
        while (lo < hi) {
            int mid = (lo + hi) >> 1;
            if (batch[mid] < key) lo = mid + 1; else hi = mid;
        }
        return lo;
    };
    int a = lb(g), b = lb(g + 1);
    float sum = 0.f;
    for (int i = a + t; i < b; i += 256) sum += s[i];
    for (int o = 32; o >= 1; o >>= 1) sum += __shfl_xor(sum, o, 64);
    if ((t & 63) == 0) partial[t >> 6] = sum;
    __syncthreads();
    if (t == 0) {
        float cnt = (float)(b - a); if (cnt < 1.f) cnt = 1.f;
        out[g] = (partial[0] + partial[1] + partial[2] + partial[3]) / cnt + bh[0];
    }
}

// ---------------- launch ----------------
extern "C" void kernel_launch(void* const* d_in, const int* in_sizes, int n_in,
                              void* d_out, int out_size, void* d_ws, size_t ws_size,
                              hipStream_t stream) {
    const float* x     = (const float*)d_in[0];
    const int*   ei    = (const int*)d_in[1];
    const int*   batch = (const int*)d_in[2];
    const float* W1  = (const float*)d_in[3];
    const float* as1 = (const float*)d_in[4];
    const float* ad1 = (const float*)d_in[5];
    const float* b1  = (const float*)d_in[6];
    const float* W2  = (const float*)d_in[7];
    const float* as2 = (const float*)d_in[8];
    const float* ad2 = (const float*)d_in[9];
    const float* b2  = (const float*)d_in[10];
    const float* Wh  = (const float*)d_in[11];
    const float* bh  = (const float*)d_in[12];
    float* out = (float*)d_out;

    const int N = in_sizes[0] / HD;
    const int E = in_sizes[1] / 2;
    const int G = out_size;
    const int* srcp = ei;
    const int* dstp = ei + E;
    const int NBK = (N + 255) / 256;      // coarse buckets (dst>>8)
    const int NT  = (E + TILE - 1) / TILE;

    char* ws = (char*)d_ws;
    size_t off = 0;
    auto alloc = [&](size_t bytes) -> void* {
        void* p = ws + off;
        off += (bytes + 255) & ~(size_t)255;
        return p;
    };
    __half* h16   = (__half*)alloc((size_t)N * HD * 2);
    __half* ob16  = (__half*)alloc((size_t)N * HD * 2);
    float* als    = (float*)alloc((size_t)N * 2 * 4);
    float* ald    = (float*)alloc((size_t)N * 2 * 4);
    float* svec   = (float*)alloc((size_t)N * 4);
    int*   indptr = (int*)  alloc((size_t)(N + 1) * 4);
    int*   csr    = (int*)  alloc((size_t)(E + N) * 4);
    int*   tileHist   = (int*)alloc((size_t)NT * 256 * 4);
    int*   bucketBase = (int*)alloc(257 * 4);
    int*   part   = (int*)  alloc((size_t)E * 4);
    ushort_t* Whs1 = (ushort_t*)alloc(16384 * 2);
    ushort_t* Wls1 = (ushort_t*)alloc(16384 * 2);
    ushort_t* Whs2 = (ushort_t*)alloc(16384 * 2);
    ushort_t* Wls2 = (ushort_t*)alloc(16384 * 2);

    // CSR build: partition by dst>>8, then fused hist+scan+scatter per bucket
    part_hist<<<NT, 256, 0, stream>>>(dstp, tileHist, E);
    part_offsets<<<1, 256, 0, stream>>>(tileHist, bucketBase, NT);
    part_scatter<<<NT, 256, 0, stream>>>(srcp, dstp, tileHist, part, E);
    csr_build<<<NBK, 256, 0, stream>>>(part, bucketBase, indptr, csr, N, E);

    // W split+swizzle (both layers, one launch)
    split_w<<<128, 256, 0, stream>>>(W1, W2, Whs1, Wls1, Whs2, Wls2);

    const int nwaves  = (N + 15) / 16;
    const int gblocks = (nwaves + 3) / 4;
    int wgrid = (N * 64 + 255) / 256;

    // layer 1 (split-bf16 MFMA; logits fused; h stored fp16)
    gemm_mfma<<<gblocks, 256, 0, stream>>>(x, Whs1, Wls1, as1, ad1, h16, als, ald, N);
    gat_aggregate<<<wgrid, 256, 0, stream>>>(h16, als, ald, indptr, csr, b1, ob16,
                                             nullptr, nullptr, N);
    // layer 2 (native f16 MFMA: A exact fp16, W 2-term fp16 split)
    gemm_mfma_f16<<<gblocks, 256, 0, stream>>>(ob16, Whs2, Wls2, as2, ad2, h16,
                                               als, ald, N);
    gat_aggregate<<<wgrid, 256, 0, stream>>>(h16, als, ald, indptr, csr, b2, nullptr,
                                             Wh, svec, N);
    // pool + head (graph bounds via inline binary search)
    pool_head<<<G, 256, 0, stream>>>(svec, batch, bh, out, N, G);
}